// Round 1
// baseline (549.300 us; speedup 1.0000x reference)
//
#include <hip/hip_runtime.h>

#define NPTS 16384
#define PTS 8   // points per workgroup

// Channels: 0=val, 1=d/dx, 2=d/dy, 3=d/dt, 4=d2/dx2, 5=d2/dy2
// LDS A layout: A[c][p][k] = A[(c*PTS+p)*256 + k]; GEMM row r = c*PTS+p (48 rows).

__global__ __launch_bounds__(256, 2) void pinn_burgers_kernel(
    const float* __restrict__ gx, const float* __restrict__ gy,
    const float* __restrict__ gt, const float* __restrict__ gnu,
    const float* __restrict__ W0, const float* __restrict__ b0,
    const float* __restrict__ W1, const float* __restrict__ b1,
    const float* __restrict__ W2, const float* __restrict__ b2,
    const float* __restrict__ W3, const float* __restrict__ b3,
    const float* __restrict__ W4, const float* __restrict__ b4,
    float* __restrict__ out)
{
    __shared__ float A[6 * PTS * 256];   // 48 KB
    __shared__ float red[PTS][12];
    __shared__ float pin[4][PTS];

    const int tid  = threadIdx.x;
    const int lane = tid & 63;
    const int wv   = tid >> 6;
    const int p0   = blockIdx.x * PTS;

    if (tid < 4 * PTS) {
        int c = tid >> 3, p = tid & 7;
        const float* src = (c == 0) ? gx : (c == 1) ? gy : (c == 2) ? gt : gnu;
        pin[c][p] = src[p0 + p];
    }
    __syncthreads();

    // ---------------- layer 0 (4 -> 256) ----------------
    {
        const int j = tid;
        const float w0 = W0[j], w1 = W0[256 + j], w2 = W0[512 + j], w3 = W0[768 + j];
        const float bb = b0[j];
        #pragma unroll
        for (int p = 0; p < PTS; ++p) {
            float hx = pin[0][p];                               // x in [-1,1] -> x
            float hy = pin[1][p];                               // y -> y
            float ht = 2.f * pin[2][p] - 1.f;                   // t in [0,1] -> 2t-1
            float hn = 2.f * (pin[3][p] - 0.01f) * (1.f / 0.09f) - 1.f;
            float z  = hx * w0 + hy * w1 + ht * w2 + hn * w3 + bb;
            float zx = w0, zy = w1, zt = 2.f * w2;              // input tangent scales 1,1,2
            float s  = 1.f / (1.f + __expf(-z));
            float g1 = s + z * s * (1.f - s);
            float g2 = s * (1.f - s) * (2.f + z * (1.f - 2.f * s));
            A[(0*PTS+p)*256 + j] = z * s;
            A[(1*PTS+p)*256 + j] = g1 * zx;
            A[(2*PTS+p)*256 + j] = g1 * zy;
            A[(3*PTS+p)*256 + j] = g1 * zt;
            A[(4*PTS+p)*256 + j] = g2 * zx * zx;                // z''_xx = 0 at layer 0
            A[(5*PTS+p)*256 + j] = g2 * zy * zy;
        }
    }
    __syncthreads();

    // ---------------- hidden layers 1..3 (256 -> 256) ----------------
    const float* Ws[3] = { W1, W2, W3 };
    const float* bs[3] = { b1, b2, b3 };
    for (int L = 0; L < 3; ++L) {
        const float* __restrict__ W  = Ws[L];
        const float* __restrict__ bv = bs[L];
        const int j0 = lane * 4;
        float acc[12][4];
        #pragma unroll
        for (int r = 0; r < 12; ++r)
            acc[r][0] = acc[r][1] = acc[r][2] = acc[r][3] = 0.f;

        // Z(48x256) = A(48x256) @ W(256x256): wave wv owns rows 12*wv..12*wv+11,
        // lane owns cols j0..j0+3. A reads are wave-uniform broadcasts (free).
        #pragma unroll 2
        for (int k = 0; k < 256; ++k) {
            const float4 w = *(const float4*)(W + k * 256 + j0);
            #pragma unroll
            for (int r = 0; r < 12; ++r) {
                float a = A[(wv * 12 + r) * 256 + k];
                acc[r][0] += a * w.x;
                acc[r][1] += a * w.y;
                acc[r][2] += a * w.z;
                acc[r][3] += a * w.w;
            }
        }
        __syncthreads();
        #pragma unroll
        for (int r = 0; r < 12; ++r) {
            int row = wv * 12 + r;
            float4 zv = { acc[r][0], acc[r][1], acc[r][2], acc[r][3] };
            if (row < PTS) {   // only value-channel rows (c==0) get bias
                zv.x += bv[j0]; zv.y += bv[j0+1]; zv.z += bv[j0+2]; zv.w += bv[j0+3];
            }
            *(float4*)(A + row * 256 + j0) = zv;
        }
        __syncthreads();
        // activation: site (p, j=tid), read 6 channels, write 6 channels
        {
            const int j = tid;
            #pragma unroll
            for (int p = 0; p < PTS; ++p) {
                float z   = A[(0*PTS+p)*256 + j];
                float zx  = A[(1*PTS+p)*256 + j];
                float zy  = A[(2*PTS+p)*256 + j];
                float zt  = A[(3*PTS+p)*256 + j];
                float zxx = A[(4*PTS+p)*256 + j];
                float zyy = A[(5*PTS+p)*256 + j];
                float s  = 1.f / (1.f + __expf(-z));
                float g1 = s + z * s * (1.f - s);
                float g2 = s * (1.f - s) * (2.f + z * (1.f - 2.f * s));
                A[(0*PTS+p)*256 + j] = z * s;
                A[(1*PTS+p)*256 + j] = g1 * zx;
                A[(2*PTS+p)*256 + j] = g1 * zy;
                A[(3*PTS+p)*256 + j] = g1 * zt;
                A[(4*PTS+p)*256 + j] = g2 * zx * zx + g1 * zxx;
                A[(5*PTS+p)*256 + j] = g2 * zy * zy + g1 * zyy;
            }
        }
        __syncthreads();
    }

    // ---------------- output layer (256 -> 2) + residual ----------------
    // 96 dots (p,c,o) of length 256; each wave does 24, lanes k-strided, shuffle-reduce.
    #pragma unroll
    for (int d = 0; d < 24; ++d) {
        int D  = wv * 24 + d;
        int p  = D / 12;
        int rm = D % 12;
        int c  = rm >> 1;
        int o  = rm & 1;
        int row = c * PTS + p;
        float partial = 0.f;
        #pragma unroll
        for (int kk = 0; kk < 4; ++kk) {
            int k = lane + 64 * kk;
            partial += A[row * 256 + k] * W4[k * 2 + o];
        }
        #pragma unroll
        for (int off = 32; off > 0; off >>= 1)
            partial += __shfl_down(partial, off);
        if (lane == 0)
            red[p][rm] = partial + ((c == 0) ? b4[o] : 0.f);
    }
    __syncthreads();

    if (tid < PTS) {
        int p = tid;
        float u   = red[p][0],  v   = red[p][1];
        float ux  = red[p][2],  vx  = red[p][3];
        float uy  = red[p][4],  vy  = red[p][5];
        float ut  = red[p][6],  vt  = red[p][7];
        float uxx = red[p][8],  vxx = red[p][9];
        float uyy = red[p][10], vyy = red[p][11];
        float nuv = pin[3][p];                      // raw nu in the PDE
        float fu = ut + u * ux + v * uy - nuv * (uxx + uyy);
        float fv = vt + u * vx + v * vy - nuv * (vxx + vyy);
        out[(p0 + p) * 2 + 0] = fu;
        out[(p0 + p) * 2 + 1] = fv;
    }
}

extern "C" void kernel_launch(void* const* d_in, const int* in_sizes, int n_in,
                              void* d_out, int out_size, void* d_ws, size_t ws_size,
                              hipStream_t stream) {
    const float* x  = (const float*)d_in[0];
    const float* y  = (const float*)d_in[1];
    const float* t  = (const float*)d_in[2];
    const float* nu = (const float*)d_in[3];
    const float* W0 = (const float*)d_in[4];
    const float* b0 = (const float*)d_in[5];
    const float* W1 = (const float*)d_in[6];
    const float* b1 = (const float*)d_in[7];
    const float* W2 = (const float*)d_in[8];
    const float* b2 = (const float*)d_in[9];
    const float* W3 = (const float*)d_in[10];
    const float* b3 = (const float*)d_in[11];
    const float* W4 = (const float*)d_in[12];
    const float* b4 = (const float*)d_in[13];
    float* o = (float*)d_out;

    hipLaunchKernelGGL(pinn_burgers_kernel, dim3(NPTS / PTS), dim3(256), 0, stream,
                       x, y, t, nu, W0, b0, W1, b1, W2, b2, W3, b3, W4, b4, o);
}

// Round 2
// 223.507 us; speedup vs baseline: 2.4576x; 2.4576x over previous
//
#include <hip/hip_runtime.h>

typedef _Float16 f16;
typedef _Float16 v8hf __attribute__((ext_vector_type(8)));
typedef _Float16 v4hf __attribute__((ext_vector_type(4)));
typedef _Float16 v2hf __attribute__((ext_vector_type(2)));
typedef float    v4f  __attribute__((ext_vector_type(4)));

#define NPTS 16384
#define PTS  8            // points per workgroup -> M = 6*PTS = 48 site-rows
#define LDA  264          // padded f16 row stride (bank-balanced for b128 frag reads)
#define NLAYER_ELEMS 65536  // 256*256 f16 per layer per split

// ---------------- prepass: split+transpose W1..W3 into MFMA A-operand order ----
// Bpack[L][ks][n][kk] (f16), kk=k&31, ks=k>>5: lane frag read = 8 contiguous f16.
__global__ void pack_weights(const float* __restrict__ W1, const float* __restrict__ W2,
                             const float* __restrict__ W3, f16* __restrict__ bh,
                             f16* __restrict__ bl) {
    const int L = blockIdx.x >> 3, ks = blockIdx.x & 7, n = threadIdx.x;
    const float* W = (L == 0) ? W1 : (L == 1) ? W2 : W3;
    f16 h[32], l[32];
    #pragma unroll
    for (int kk = 0; kk < 32; ++kk) {
        float w = W[(ks * 32 + kk) * 256 + n];      // coalesced along n
        f16 hh = (f16)w;
        h[kk] = hh;
        l[kk] = (f16)(w - (float)hh);
    }
    size_t off = (size_t)L * NLAYER_ELEMS + (size_t)(ks * 256 + n) * 32;
    #pragma unroll
    for (int i = 0; i < 4; ++i) {
        *(v8hf*)(bh + off + 8 * i) = *(v8hf*)(h + 8 * i);
        *(v8hf*)(bl + off + 8 * i) = *(v8hf*)(l + 8 * i);
    }
}

// ---------------- main kernel --------------------------------------------------
// Channels: 0=val 1=dx 2=dy 3=dt 4=dxx 5=dyy; site-row m = c*PTS + p.
// Hidden GEMM computes Z^T via mfma(A-op=W^T frag, B-op=A^T frag):
//   D row (quad*4+reg) = neuron col n, D col (lane&15) = site-row m.
__global__ __launch_bounds__(256, 3) void pinn_burgers_kernel(
    const float* __restrict__ gx, const float* __restrict__ gy,
    const float* __restrict__ gt, const float* __restrict__ gnu,
    const float* __restrict__ W0, const float* __restrict__ b0,
    const float* __restrict__ b1, const float* __restrict__ b2,
    const float* __restrict__ b3,
    const float* __restrict__ W4, const float* __restrict__ b4,
    const f16* __restrict__ bh, const f16* __restrict__ bl,
    float* __restrict__ out)
{
    __shared__ f16 Ah[48 * LDA];   // 25344 B
    __shared__ f16 Al[48 * LDA];   // 25344 B
    __shared__ float red[PTS][12];
    __shared__ float pin[4][PTS];

    const int tid  = threadIdx.x;
    const int lane = tid & 63;
    const int wv   = tid >> 6;        // 4 waves
    const int ln   = lane & 15;
    const int quad = lane >> 4;
    const int p0   = blockIdx.x * PTS;

    if (tid < 4 * PTS) {
        int c = tid >> 3, p = tid & 7;
        const float* src = (c == 0) ? gx : (c == 1) ? gy : (c == 2) ? gt : gnu;
        pin[c][p] = src[p0 + p];
    }
    __syncthreads();

    // ---------------- layer 0 (4 -> 256), fp32 VALU, write split f16 ----------
    {
        const int jp = tid & 127, j0 = jp * 2, pg = tid >> 7;
        float w00[2], w01[2], w02[2], w03[2], bb[2];
        #pragma unroll
        for (int e = 0; e < 2; ++e) {
            int j = j0 + e;
            w00[e] = W0[j]; w01[e] = W0[256 + j]; w02[e] = W0[512 + j]; w03[e] = W0[768 + j];
            bb[e] = b0[j];
        }
        #pragma unroll
        for (int pp = 0; pp < 4; ++pp) {
            int p = pg * 4 + pp;
            float hx = pin[0][p];
            float hy = pin[1][p];
            float ht = 2.f * pin[2][p] - 1.f;
            float hn = 2.f * (pin[3][p] - 0.01f) * (1.f / 0.09f) - 1.f;
            float a[6][2];
            #pragma unroll
            for (int e = 0; e < 2; ++e) {
                float z  = hx * w00[e] + hy * w01[e] + ht * w02[e] + hn * w03[e] + bb[e];
                float zx = w00[e], zy = w01[e], zt = 2.f * w02[e];
                float s  = 1.f / (1.f + __expf(-z));
                float g1 = s + z * s * (1.f - s);
                float g2 = s * (1.f - s) * (2.f + z * (1.f - 2.f * s));
                a[0][e] = z * s;
                a[1][e] = g1 * zx; a[2][e] = g1 * zy; a[3][e] = g1 * zt;
                a[4][e] = g2 * zx * zx; a[5][e] = g2 * zy * zy;
            }
            #pragma unroll
            for (int c = 0; c < 6; ++c) {
                v2hf hh = { (f16)a[c][0], (f16)a[c][1] };
                v2hf ll = { (f16)(a[c][0] - (float)hh[0]), (f16)(a[c][1] - (float)hh[1]) };
                *(v2hf*)&Ah[(c * PTS + p) * LDA + j0] = hh;
                *(v2hf*)&Al[(c * PTS + p) * LDA + j0] = ll;
            }
        }
    }
    __syncthreads();

    // ---------------- hidden layers 1..3: split-f16 MFMA ----------------------
    const float* bias_ptr[3] = { b1, b2, b3 };
    for (int L = 0; L < 3; ++L) {
        const f16* __restrict__ bhL = bh + (size_t)L * NLAYER_ELEMS;
        const f16* __restrict__ blL = bl + (size_t)L * NLAYER_ELEMS;
        const float* __restrict__ bv = bias_ptr[L];

        v4f acc[4][3];     // [nTile t][mTile] ; wave owns neuron cols wv*64 .. wv*64+63
        #pragma unroll
        for (int t = 0; t < 4; ++t)
            #pragma unroll
            for (int mt = 0; mt < 3; ++mt)
                acc[t][mt] = (v4f){0.f, 0.f, 0.f, 0.f};

        #pragma unroll 2
        for (int ks = 0; ks < 8; ++ks) {
            v8hf a_h[3], a_l[3];
            #pragma unroll
            for (int mt = 0; mt < 3; ++mt) {
                const f16* p = Ah + (mt * 16 + ln) * LDA + ks * 32 + quad * 8;
                a_h[mt] = *(const v8hf*)p;
                a_l[mt] = *(const v8hf*)(p + 48 * LDA);   // Al directly after Ah? NO — separate arrays
            }
            // (note: Al is a separate array; redo the lo reads properly)
            #pragma unroll
            for (int mt = 0; mt < 3; ++mt) {
                const f16* p = Al + (mt * 16 + ln) * LDA + ks * 32 + quad * 8;
                a_l[mt] = *(const v8hf*)p;
            }
            v8hf w_h[4], w_l[4];
            #pragma unroll
            for (int t = 0; t < 4; ++t) {
                int n = wv * 64 + t * 16 + ln;
                size_t o = (size_t)(ks * 256 + n) * 32 + quad * 8;
                w_h[t] = *(const v8hf*)(bhL + o);
                w_l[t] = *(const v8hf*)(blL + o);
            }
            #pragma unroll
            for (int t = 0; t < 4; ++t)
                #pragma unroll
                for (int mt = 0; mt < 3; ++mt) {
                    acc[t][mt] = __builtin_amdgcn_mfma_f32_16x16x32_f16(w_h[t], a_h[mt], acc[t][mt], 0, 0, 0);
                    acc[t][mt] = __builtin_amdgcn_mfma_f32_16x16x32_f16(w_h[t], a_l[mt], acc[t][mt], 0, 0, 0);
                    acc[t][mt] = __builtin_amdgcn_mfma_f32_16x16x32_f16(w_l[t], a_h[mt], acc[t][mt], 0, 0, 0);
                }
        }
        __syncthreads();   // all reads of A done before overwrite

        // epilogue: D row = neuron n (quad*4+reg), D col = site-row m (lane&15)
        #pragma unroll
        for (int t = 0; t < 4; ++t)
            #pragma unroll
            for (int mt = 0; mt < 3; ++mt) {
                v4f a = acc[t][mt];
                int nb = wv * 64 + t * 16 + quad * 4;
                int m  = mt * 16 + ln;
                if (mt == 0 && ln < PTS) {   // value-channel site rows get bias
                    const float4 bq = *(const float4*)(bv + nb);
                    a[0] += bq.x; a[1] += bq.y; a[2] += bq.z; a[3] += bq.w;
                }
                v4hf hi = { (f16)a[0], (f16)a[1], (f16)a[2], (f16)a[3] };
                v4hf lo = { (f16)(a[0] - (float)hi[0]), (f16)(a[1] - (float)hi[1]),
                            (f16)(a[2] - (float)hi[2]), (f16)(a[3] - (float)hi[3]) };
                *(v4hf*)&Ah[m * LDA + nb] = hi;
                *(v4hf*)&Al[m * LDA + nb] = lo;
            }
        __syncthreads();

        // activation + AD chain, in place (each thread owns its (p, j0/j0+1) sites)
        {
            const int jp = tid & 127, j0 = jp * 2, pg = tid >> 7;
            #pragma unroll
            for (int pp = 0; pp < 4; ++pp) {
                int p = pg * 4 + pp;
                float z[6][2];
                #pragma unroll
                for (int c = 0; c < 6; ++c) {
                    v2hf hh = *(v2hf*)&Ah[(c * PTS + p) * LDA + j0];
                    v2hf ll = *(v2hf*)&Al[(c * PTS + p) * LDA + j0];
                    z[c][0] = (float)hh[0] + (float)ll[0];
                    z[c][1] = (float)hh[1] + (float)ll[1];
                }
                float a[6][2];
                #pragma unroll
                for (int e = 0; e < 2; ++e) {
                    float zz = z[0][e];
                    float s  = 1.f / (1.f + __expf(-zz));
                    float g1 = s + zz * s * (1.f - s);
                    float g2 = s * (1.f - s) * (2.f + zz * (1.f - 2.f * s));
                    a[0][e] = zz * s;
                    a[1][e] = g1 * z[1][e];
                    a[2][e] = g1 * z[2][e];
                    a[3][e] = g1 * z[3][e];
                    a[4][e] = g2 * z[1][e] * z[1][e] + g1 * z[4][e];
                    a[5][e] = g2 * z[2][e] * z[2][e] + g1 * z[5][e];
                }
                #pragma unroll
                for (int c = 0; c < 6; ++c) {
                    v2hf hh = { (f16)a[c][0], (f16)a[c][1] };
                    v2hf ll = { (f16)(a[c][0] - (float)hh[0]), (f16)(a[c][1] - (float)hh[1]) };
                    *(v2hf*)&Ah[(c * PTS + p) * LDA + j0] = hh;
                    *(v2hf*)&Al[(c * PTS + p) * LDA + j0] = ll;
                }
            }
        }
        __syncthreads();
    }

    // ---------------- output layer (256 -> 2) + residual, fp32 VALU -----------
    #pragma unroll
    for (int d = 0; d < 24; ++d) {
        int D  = wv * 24 + d;
        int p  = D / 12;
        int rm = D % 12;
        int c  = rm >> 1;
        int o  = rm & 1;
        int m  = c * PTS + p;
        int k0 = lane * 4;
        v4hf hh = *(v4hf*)&Ah[m * LDA + k0];
        v4hf ll = *(v4hf*)&Al[m * LDA + k0];
        float partial = 0.f;
        #pragma unroll
        for (int i = 0; i < 4; ++i)
            partial += ((float)hh[i] + (float)ll[i]) * W4[(k0 + i) * 2 + o];
        #pragma unroll
        for (int off = 32; off > 0; off >>= 1)
            partial += __shfl_down(partial, off);
        if (lane == 0)
            red[p][rm] = partial + ((c == 0) ? b4[o] : 0.f);
    }
    __syncthreads();

    if (tid < PTS) {
        int p = tid;
        float u   = red[p][0],  v   = red[p][1];
        float ux  = red[p][2],  vx  = red[p][3];
        float uy  = red[p][4],  vy  = red[p][5];
        float ut  = red[p][6],  vt  = red[p][7];
        float uxx = red[p][8],  vxx = red[p][9];
        float uyy = red[p][10], vyy = red[p][11];
        float nuv = pin[3][p];
        float fu = ut + u * ux + v * uy - nuv * (uxx + uyy);
        float fv = vt + u * vx + v * vy - nuv * (vxx + vyy);
        out[(p0 + p) * 2 + 0] = fu;
        out[(p0 + p) * 2 + 1] = fv;
    }
}

extern "C" void kernel_launch(void* const* d_in, const int* in_sizes, int n_in,
                              void* d_out, int out_size, void* d_ws, size_t ws_size,
                              hipStream_t stream) {
    const float* x  = (const float*)d_in[0];
    const float* y  = (const float*)d_in[1];
    const float* t  = (const float*)d_in[2];
    const float* nu = (const float*)d_in[3];
    const float* W0 = (const float*)d_in[4];
    const float* b0 = (const float*)d_in[5];
    const float* W1 = (const float*)d_in[6];
    const float* b1 = (const float*)d_in[7];
    const float* W2 = (const float*)d_in[8];
    const float* b2 = (const float*)d_in[9];
    const float* W3 = (const float*)d_in[10];
    const float* b3 = (const float*)d_in[11];
    const float* W4 = (const float*)d_in[12];
    const float* b4 = (const float*)d_in[13];
    float* o = (float*)d_out;

    f16* bh = (f16*)d_ws;                          // 3*65536 f16 = 384 KB
    f16* bl = bh + 3 * (size_t)NLAYER_ELEMS;       // 384 KB more

    hipLaunchKernelGGL(pack_weights, dim3(24), dim3(256), 0, stream, W1, W2, W3, bh, bl);
    hipLaunchKernelGGL(pinn_burgers_kernel, dim3(NPTS / PTS), dim3(256), 0, stream,
                       x, y, t, nu, W0, b0, b1, b2, b3, W4, b4, bh, bl, o);
}

// Round 3
// 221.236 us; speedup vs baseline: 2.4829x; 1.0103x over previous
//
#include <hip/hip_runtime.h>

typedef _Float16 f16;
typedef _Float16 v8hf __attribute__((ext_vector_type(8)));
typedef _Float16 v4hf __attribute__((ext_vector_type(4)));
typedef _Float16 v2hf __attribute__((ext_vector_type(2)));
typedef float    v4f  __attribute__((ext_vector_type(4)));

#define NPTS 16384
#define PTS  8            // points per workgroup -> M = 6*PTS = 48 site-rows
#define NLAYER_ELEMS 65536  // 256*256 f16 per layer per split

// XOR-swizzled LDS index for logical (row m, f16-col j); row stride 256 f16
// (512 B == 0 mod 128 B). 16B chunks; phys chunk = chunk ^ (m&7). Every access
// in this kernel is contained in one 16B chunk, so data stays contiguous.
__device__ __forceinline__ int swz(int m, int j) {
    return m * 256 + ((((j >> 3) ^ (m & 7)) << 3) | (j & 7));
}

// ---------------- prepass: split+transpose W1..W3 into MFMA A-operand order ----
// Bpack[L][ks][n][kk] (f16), kk=k&31, ks=k>>5: lane frag read = 8 contiguous f16.
__global__ void pack_weights(const float* __restrict__ W1, const float* __restrict__ W2,
                             const float* __restrict__ W3, f16* __restrict__ bh,
                             f16* __restrict__ bl) {
    const int L = blockIdx.x >> 3, ks = blockIdx.x & 7, n = threadIdx.x;
    const float* W = (L == 0) ? W1 : (L == 1) ? W2 : W3;
    f16 h[32], l[32];
    #pragma unroll
    for (int kk = 0; kk < 32; ++kk) {
        float w = W[(ks * 32 + kk) * 256 + n];      // coalesced along n
        f16 hh = (f16)w;
        h[kk] = hh;
        l[kk] = (f16)(w - (float)hh);
    }
    size_t off = (size_t)L * NLAYER_ELEMS + (size_t)(ks * 256 + n) * 32;
    #pragma unroll
    for (int i = 0; i < 4; ++i) {
        *(v8hf*)(bh + off + 8 * i) = *(v8hf*)(h + 8 * i);
        *(v8hf*)(bl + off + 8 * i) = *(v8hf*)(l + 8 * i);
    }
}

// ---------------- main kernel --------------------------------------------------
// Channels: 0=val 1=dx 2=dy 3=dt 4=dxx 5=dyy; site-row m = c*PTS + p.
// Hidden GEMM computes Z^T via mfma(A-op=W^T frag, B-op=A^T frag):
//   D row (quad*4+reg) = neuron col n, D col (lane&15) = site-row m.
__global__ __launch_bounds__(256, 3) void pinn_burgers_kernel(
    const float* __restrict__ gx, const float* __restrict__ gy,
    const float* __restrict__ gt, const float* __restrict__ gnu,
    const float* __restrict__ W0, const float* __restrict__ b0,
    const float* __restrict__ b1, const float* __restrict__ b2,
    const float* __restrict__ b3,
    const float* __restrict__ W4, const float* __restrict__ b4,
    const f16* __restrict__ bh, const f16* __restrict__ bl,
    float* __restrict__ out)
{
    __shared__ f16 Ah[48 * 256];   // 24576 B, swizzled layout
    __shared__ f16 Al[48 * 256];   // 24576 B
    __shared__ float red[PTS][12];
    __shared__ float pin[4][PTS];

    const int tid  = threadIdx.x;
    const int lane = tid & 63;
    const int wv   = tid >> 6;        // 4 waves
    const int ln   = lane & 15;
    const int quad = lane >> 4;
    const int lnx  = ln & 7;
    const int p0   = blockIdx.x * PTS;

    if (tid < 4 * PTS) {
        int c = tid >> 3, p = tid & 7;
        const float* src = (c == 0) ? gx : (c == 1) ? gy : (c == 2) ? gt : gnu;
        pin[c][p] = src[p0 + p];
    }
    __syncthreads();

    // Per-wave column ownership for layer0 / activation phases:
    // wave wv owns cols [wv*64, wv*64+64); lane handles cols j0,j0+1 and 4 sites.
    const int l5 = lane & 31;
    const int j0 = wv * 64 + l5 * 2;
    const int ph = (lane >> 5) * 4;

    // ---------------- layer 0 (4 -> 256), fp32 VALU, write split f16 ----------
    {
        float w00[2], w01[2], w02[2], w03[2], bb[2];
        #pragma unroll
        for (int e = 0; e < 2; ++e) {
            int j = j0 + e;
            w00[e] = W0[j]; w01[e] = W0[256 + j]; w02[e] = W0[512 + j]; w03[e] = W0[768 + j];
            bb[e] = b0[j];
        }
        #pragma unroll
        for (int pp = 0; pp < 4; ++pp) {
            int p = ph + pp;
            float hx = pin[0][p];
            float hy = pin[1][p];
            float ht = 2.f * pin[2][p] - 1.f;
            float hn = 2.f * (pin[3][p] - 0.01f) * (1.f / 0.09f) - 1.f;
            float a[6][2];
            #pragma unroll
            for (int e = 0; e < 2; ++e) {
                float z  = hx * w00[e] + hy * w01[e] + ht * w02[e] + hn * w03[e] + bb[e];
                float zx = w00[e], zy = w01[e], zt = 2.f * w02[e];
                float s  = 1.f / (1.f + __expf(-z));
                float g1 = s + z * s * (1.f - s);
                float g2 = s * (1.f - s) * (2.f + z * (1.f - 2.f * s));
                a[0][e] = z * s;
                a[1][e] = g1 * zx; a[2][e] = g1 * zy; a[3][e] = g1 * zt;
                a[4][e] = g2 * zx * zx; a[5][e] = g2 * zy * zy;
            }
            #pragma unroll
            for (int c = 0; c < 6; ++c) {
                int idx = swz(c * PTS + p, j0);
                v2hf hh = { (f16)a[c][0], (f16)a[c][1] };
                v2hf ll = { (f16)(a[c][0] - (float)hh[0]), (f16)(a[c][1] - (float)hh[1]) };
                *(v2hf*)&Ah[idx] = hh;
                *(v2hf*)&Al[idx] = ll;
            }
        }
    }
    __syncthreads();

    // ---------------- hidden layers 1..3: split-f16 MFMA ----------------------
    const float* bias_ptr[3] = { b1, b2, b3 };
    for (int L = 0; L < 3; ++L) {
        const f16* __restrict__ bhL = bh + (size_t)L * NLAYER_ELEMS;
        const f16* __restrict__ blL = bl + (size_t)L * NLAYER_ELEMS;
        const float* __restrict__ bv = bias_ptr[L];

        v4f acc[4][3];     // [nTile t][mTile] ; wave owns neuron cols wv*64 .. wv*64+63
        #pragma unroll
        for (int t = 0; t < 4; ++t)
            #pragma unroll
            for (int mt = 0; mt < 3; ++mt)
                acc[t][mt] = (v4f){0.f, 0.f, 0.f, 0.f};

        #pragma unroll 2
        for (int ks = 0; ks < 8; ++ks) {
            // A-fragment LDS reads: chunk (4ks+quad) ^ (ln&7) -> conflict-free
            const int cb = (((4 * ks + quad) ^ lnx) << 3);
            v8hf a_h[3], a_l[3];
            #pragma unroll
            for (int mt = 0; mt < 3; ++mt) {
                const int rb = (mt * 16 + ln) * 256 + cb;
                a_h[mt] = *(const v8hf*)&Ah[rb];
                a_l[mt] = *(const v8hf*)&Al[rb];
            }
            v8hf w_h[4], w_l[4];
            #pragma unroll
            for (int t = 0; t < 4; ++t) {
                int n = wv * 64 + t * 16 + ln;
                size_t o = (size_t)(ks * 256 + n) * 32 + quad * 8;
                w_h[t] = *(const v8hf*)(bhL + o);
                w_l[t] = *(const v8hf*)(blL + o);
            }
            #pragma unroll
            for (int t = 0; t < 4; ++t)
                #pragma unroll
                for (int mt = 0; mt < 3; ++mt) {
                    acc[t][mt] = __builtin_amdgcn_mfma_f32_16x16x32_f16(w_h[t], a_h[mt], acc[t][mt], 0, 0, 0);
                    acc[t][mt] = __builtin_amdgcn_mfma_f32_16x16x32_f16(w_h[t], a_l[mt], acc[t][mt], 0, 0, 0);
                    acc[t][mt] = __builtin_amdgcn_mfma_f32_16x16x32_f16(w_l[t], a_h[mt], acc[t][mt], 0, 0, 0);
                }
        }
        __syncthreads();   // all reads of A done before overwrite

        // epilogue: D row = neuron n (quad*4+reg), D col = site-row m (lane&15)
        #pragma unroll
        for (int t = 0; t < 4; ++t)
            #pragma unroll
            for (int mt = 0; mt < 3; ++mt) {
                v4f a = acc[t][mt];
                int nb = wv * 64 + t * 16 + quad * 4;
                int m  = mt * 16 + ln;
                if (mt == 0 && ln < PTS) {   // value-channel site rows get bias
                    const float4 bq = *(const float4*)(bv + nb);
                    a[0] += bq.x; a[1] += bq.y; a[2] += bq.z; a[3] += bq.w;
                }
                v4hf hi = { (f16)a[0], (f16)a[1], (f16)a[2], (f16)a[3] };
                v4hf lo = { (f16)(a[0] - (float)hi[0]), (f16)(a[1] - (float)hi[1]),
                            (f16)(a[2] - (float)hi[2]), (f16)(a[3] - (float)hi[3]) };
                int idx = swz(m, nb);
                *(v4hf*)&Ah[idx] = hi;
                *(v4hf*)&Al[idx] = lo;
            }
        // NO barrier: activation below touches only this wave's columns.

        // activation + AD chain, in place (wave-local columns)
        {
            #pragma unroll
            for (int pp = 0; pp < 4; ++pp) {
                int p = ph + pp;
                float z[6][2];
                #pragma unroll
                for (int c = 0; c < 6; ++c) {
                    int idx = swz(c * PTS + p, j0);
                    v2hf hh = *(v2hf*)&Ah[idx];
                    v2hf ll = *(v2hf*)&Al[idx];
                    z[c][0] = (float)hh[0] + (float)ll[0];
                    z[c][1] = (float)hh[1] + (float)ll[1];
                }
                float a[6][2];
                #pragma unroll
                for (int e = 0; e < 2; ++e) {
                    float zz = z[0][e];
                    float s  = 1.f / (1.f + __expf(-zz));
                    float g1 = s + zz * s * (1.f - s);
                    float g2 = s * (1.f - s) * (2.f + zz * (1.f - 2.f * s));
                    a[0][e] = zz * s;
                    a[1][e] = g1 * z[1][e];
                    a[2][e] = g1 * z[2][e];
                    a[3][e] = g1 * z[3][e];
                    a[4][e] = g2 * z[1][e] * z[1][e] + g1 * z[4][e];
                    a[5][e] = g2 * z[2][e] * z[2][e] + g1 * z[5][e];
                }
                #pragma unroll
                for (int c = 0; c < 6; ++c) {
                    int idx = swz(c * PTS + p, j0);
                    v2hf hh = { (f16)a[c][0], (f16)a[c][1] };
                    v2hf ll = { (f16)(a[c][0] - (float)hh[0]), (f16)(a[c][1] - (float)hh[1]) };
                    *(v2hf*)&Ah[idx] = hh;
                    *(v2hf*)&Al[idx] = ll;
                }
            }
        }
        __syncthreads();
    }

    // ---------------- output layer (256 -> 2) + residual, fp32 VALU -----------
    #pragma unroll
    for (int d = 0; d < 24; ++d) {
        int D  = wv * 24 + d;
        int p  = D / 12;
        int rm = D % 12;
        int c  = rm >> 1;
        int o  = rm & 1;
        int m  = c * PTS + p;
        int k0 = lane * 4;
        int idx = swz(m, k0);
        v4hf hh = *(v4hf*)&Ah[idx];
        v4hf ll = *(v4hf*)&Al[idx];
        float partial = 0.f;
        #pragma unroll
        for (int i = 0; i < 4; ++i)
            partial += ((float)hh[i] + (float)ll[i]) * W4[(k0 + i) * 2 + o];
        #pragma unroll
        for (int off = 32; off > 0; off >>= 1)
            partial += __shfl_down(partial, off);
        if (lane == 0)
            red[p][rm] = partial + ((c == 0) ? b4[o] : 0.f);
    }
    __syncthreads();

    if (tid < PTS) {
        int p = tid;
        float u   = red[p][0],  v   = red[p][1];
        float ux  = red[p][2],  vx  = red[p][3];
        float uy  = red[p][4],  vy  = red[p][5];
        float ut  = red[p][6],  vt  = red[p][7];
        float uxx = red[p][8],  vxx = red[p][9];
        float uyy = red[p][10], vyy = red[p][11];
        float nuv = pin[3][p];
        float fu = ut + u * ux + v * uy - nuv * (uxx + uyy);
        float fv = vt + u * vx + v * vy - nuv * (vxx + vyy);
        out[(p0 + p) * 2 + 0] = fu;
        out[(p0 + p) * 2 + 1] = fv;
    }
}

extern "C" void kernel_launch(void* const* d_in, const int* in_sizes, int n_in,
                              void* d_out, int out_size, void* d_ws, size_t ws_size,
                              hipStream_t stream) {
    const float* x  = (const float*)d_in[0];
    const float* y  = (const float*)d_in[1];
    const float* t  = (const float*)d_in[2];
    const float* nu = (const float*)d_in[3];
    const float* W0 = (const float*)d_in[4];
    const float* b0 = (const float*)d_in[5];
    const float* W1 = (const float*)d_in[6];
    const float* b1 = (const float*)d_in[7];
    const float* W2 = (const float*)d_in[8];
    const float* b2 = (const float*)d_in[9];
    const float* W3 = (const float*)d_in[10];
    const float* b3 = (const float*)d_in[11];
    const float* W4 = (const float*)d_in[12];
    const float* b4 = (const float*)d_in[13];
    float* o = (float*)d_out;

    f16* bh = (f16*)d_ws;                          // 3*65536 f16 = 384 KB
    f16* bl = bh + 3 * (size_t)NLAYER_ELEMS;       // 384 KB more

    hipLaunchKernelGGL(pack_weights, dim3(24), dim3(256), 0, stream, W1, W2, W3, bh, bl);
    hipLaunchKernelGGL(pinn_burgers_kernel, dim3(NPTS / PTS), dim3(256), 0, stream,
                       x, y, t, nu, W0, b0, b1, b2, b3, W4, b4, bh, bl, o);
}